// Round 1
// 152.141 us; speedup vs baseline: 1.0044x; 1.0044x over previous
//
#include <hip/hip_runtime.h>

// GPSA bf16-MFMA v9. B=64, N=300, C=256, H=8, hd=32.
// K0 prep: x/Wqk|Wv/Wproj -> bf16 in TILED+SWIZZLED layout [tile][kt][128][64]
//          (chunk slot c^(row&7)); gpos[h,i,j] = bf16(g_h*softmax_j(...)) [8,304,304]
// K2 gemm_qkv_mfma: m97-style global_load_lds DMA; MFMA operands SWAPPED so lanes
//          hold 4 consecutive cols -> uint2 epilogue stores; q pre-scaled by
//          log2(e)/sqrt(32) so attention can use raw v_exp_f32 (exp2).
// K3 attn_mfma: PAIR-PACKED PV loop: two 16-col tiles share one K=32 MFMA set
//          (full k-slot utilization; 6 MFMAs / 32 cols vs 10 before), exp2 instead
//          of mul+exp, v_cvt_pk_bf16_f32 instead of 5-instr manual RNE pack.
// K4 gemm_proj_mfma: swapped operands -> float4 stores + float4 bias loads.

#define NSEQ 300
#define HEADS 8
#define HD 32

typedef short v8s __attribute__((ext_vector_type(8)));
typedef float v4f __attribute__((ext_vector_type(4)));
typedef unsigned int v4u __attribute__((ext_vector_type(4)));

__device__ __forceinline__ ushort f2bf(float f) {
    unsigned u = __float_as_uint(f);
    u = (u + 0x7FFFu + ((u >> 16) & 1u)) >> 16;   // RNE
    return (ushort)u;
}

// pack two fp32 -> packed bf16x2 (lo=a, hi=b) via v_perm (used in prep only)
__device__ __forceinline__ unsigned pk2bf(float a, float b) {
    unsigned ua = __float_as_uint(a), ub = __float_as_uint(b);
    ua += 0x7FFFu + ((ua >> 16) & 1u);
    ub += 0x7FFFu + ((ub >> 16) & 1u);
    return __builtin_amdgcn_perm(ub, ua, 0x07060302);  // [ua.hi16 | ub.hi16]
}

// single-instruction RNE pack (lo=a, hi=b) — hot-loop version
__device__ __forceinline__ unsigned cvtpk(float a, float b) {
    unsigned r;
    asm("v_cvt_pk_bf16_f32 %0, %1, %2" : "=v"(r) : "v"(a), "v"(b));
    return r;
}

__device__ __forceinline__ float fexp2(float x) {
#if __has_builtin(__builtin_amdgcn_exp2f)
    return __builtin_amdgcn_exp2f(x);
#else
    float r; asm("v_exp_f32 %0, %1" : "=v"(r) : "v"(x)); return r;
#endif
}

// async global->LDS DMA, 16B per lane
__device__ __forceinline__ void gl_lds16(const ushort* g, ushort* l) {
    __builtin_amdgcn_global_load_lds(
        (const __attribute__((address_space(1))) void*)g,
        (__attribute__((address_space(3))) void*)l, 16, 0, 0);
}

// ---------------- K0: prep = convert+tile+swizzle + gated positional softmax ----------------
__global__ __launch_bounds__(256) void prep_kernel(
    const float* __restrict__ x, const float* __restrict__ Wqk,
    const float* __restrict__ Wv, const float* __restrict__ Wproj,
    const float* __restrict__ Wpos, const float* __restrict__ bpos,
    const float* __restrict__ gating,
    ushort* __restrict__ x_t, ushort* __restrict__ wqkv_t,
    ushort* __restrict__ wproj_t, ushort* __restrict__ gpos)
{
    int bid = blockIdx.x, tid = threadIdx.x;
    if (bid < 2528) {
        const float* src; ushort* dstbase; int m, ck;
        if (bid < 2400) {                         // x: 19200 rows x 32 chunks
            int idx = bid * 256 + tid;
            m = idx >> 5; ck = idx & 31;
            src = x + (size_t)m * 256 + ck * 8;
            dstbase = x_t;
        } else if (bid < 2496) {                  // W qkv: 768 rows x 32 chunks
            int idx = (bid - 2400) * 256 + tid;
            m = idx >> 5; ck = idx & 31;
            src = (m < 512 ? Wqk + (size_t)m * 256 : Wv + (size_t)(m - 512) * 256) + ck * 8;
            dstbase = wqkv_t;
        } else {                                  // W proj: 256 rows x 32 chunks
            int idx = (bid - 2496) * 256 + tid;
            m = idx >> 5; ck = idx & 31;
            src = Wproj + (size_t)m * 256 + ck * 8;
            dstbase = wproj_t;
        }
        int rt = m >> 7, rr = m & 127, kt = ck >> 3, c = ck & 7;
        float4 f0 = *(const float4*)src;
        float4 f1 = *(const float4*)(src + 4);
        v4u pk = {pk2bf(f0.x, f0.y), pk2bf(f0.z, f0.w),
                  pk2bf(f1.x, f1.y), pk2bf(f1.z, f1.w)};
        *(v4u*)(dstbase + ((size_t)(rt * 4 + kt) * 128 + rr) * 64 + ((c ^ (rr & 7)) * 8)) = pk;
        return;
    }
    int sub = bid - 2528;                       // 0..607
    int h = sub / 76;
    int i = (sub % 76) * 4 + (tid >> 6);        // row 0..303
    int lane = tid & 63;
    ushort* gr = gpos + ((size_t)h * 304 + i) * 304;
    if (i >= NSEQ) {
#pragma unroll
        for (int t = 0; t < 5; ++t) {
            int j = lane + 64 * t;
            if (j < 304) gr[j] = 0;
        }
        return;
    }
    float w0 = Wpos[h * 3 + 0], w2 = Wpos[h * 3 + 2], bb = bpos[h];
    float g = 1.f / (1.f + __expf(-gating[h]));
    float sv[5]; float m2 = -1e30f;
#pragma unroll
    for (int t = 0; t < 5; ++t) {
        int j = lane + 64 * t;
        float d = (float)(j - i);
        float lg = fmaf(w2, d * d, fmaf(w0, d, bb));
        sv[t] = (j < NSEQ) ? lg : -1e30f;
        m2 = fmaxf(m2, sv[t]);
    }
#pragma unroll
    for (int off = 32; off > 0; off >>= 1) m2 = fmaxf(m2, __shfl_xor(m2, off));
    float sum = 0.f;
#pragma unroll
    for (int t = 0; t < 5; ++t) { sv[t] = __expf(sv[t] - m2); sum += sv[t]; }
#pragma unroll
    for (int off = 32; off > 0; off >>= 1) sum += __shfl_xor(sum, off);
    float gi = g / sum;
#pragma unroll
    for (int t = 0; t < 5; ++t) {
        int j = lane + 64 * t;
        if (j < NSEQ) gr[j] = f2bf(sv[t] * gi);
        else if (j < 304) gr[j] = 0;
    }
}

// ---------------- K2: QKV GEMM, DMA staging, swapped-operand MFMA ----------------
__global__ __launch_bounds__(256, 4) void gemm_qkv_mfma(
    const ushort* __restrict__ A, const ushort* __restrict__ Bw,
    ushort* __restrict__ qo, ushort* __restrict__ ko, ushort* __restrict__ vo)
{
    __shared__ ushort As[128 * 64];
    __shared__ ushort Bs[128 * 64];
    int tid = threadIdx.x;
    int wave = tid >> 6, lane = tid & 63, li = lane & 15, qd = lane >> 4;
    int rh = wave >> 1, ch = wave & 1;
    const ushort* gA = A + (size_t)blockIdx.y * 4 * 8192;
    const ushort* gB = Bw + (size_t)blockIdx.x * 4 * 8192;

    v4f acc[4][4];
#pragma unroll
    for (int i = 0; i < 4; ++i)
#pragma unroll
        for (int j = 0; j < 4; ++j) acc[i][j] = (v4f){0.f, 0.f, 0.f, 0.f};

    for (int kt = 0; kt < 4; ++kt) {
#pragma unroll
        for (int s = 0; s < 4; ++s) {
            int cch = s * 256 + tid;
            gl_lds16(gA + (size_t)kt * 8192 + cch * 8, As + cch * 8);
            gl_lds16(gB + (size_t)kt * 8192 + cch * 8, Bs + cch * 8);
        }
        __syncthreads();
#pragma unroll
        for (int kc = 0; kc < 64; kc += 32) {
            int cb = (kc >> 3) + qd;
            int cs = cb ^ (li & 7);
            v8s a[4], b[4];
#pragma unroll
            for (int mt = 0; mt < 4; ++mt)
                a[mt] = *(const v8s*)&As[(rh * 64 + mt * 16 + li) * 64 + cs * 8];
#pragma unroll
            for (int nt = 0; nt < 4; ++nt)
                b[nt] = *(const v8s*)&Bs[(ch * 64 + nt * 16 + li) * 64 + cs * 8];
            // SWAPPED: D = B_rows x A_rows^T -> lane holds 4 consecutive COLS
#pragma unroll
            for (int mt = 0; mt < 4; ++mt)
#pragma unroll
                for (int nt = 0; nt < 4; ++nt)
                    acc[mt][nt] = __builtin_amdgcn_mfma_f32_16x16x32_bf16(b[nt], a[mt], acc[mt][nt], 0, 0, 0);
        }
        __syncthreads();
    }

    int reg3 = blockIdx.x >> 1;  // 0=q 1=k 2=v
    ushort* ob = (reg3 == 0) ? qo : (reg3 == 1) ? ko : vo;
    // q scale = log2(e)/sqrt(32): attention uses raw exp2 on the scores
    float sc = (reg3 == 0) ? 0.25503486063f : 1.0f;
    int cb2 = (blockIdx.x & 1) * 128 + ch * 64;
#pragma unroll
    for (int mt = 0; mt < 4; ++mt) {
        unsigned row = blockIdx.y * 128 + rh * 64 + mt * 16 + li;
        unsigned bb = row / 300u;
        unsigned nn = row - bb * 300u;
#pragma unroll
        for (int nt = 0; nt < 4; ++nt) {
            int col = cb2 + nt * 16 + qd * 4;        // 4 consecutive cols, same head
            int hh = col >> 5, dd = col & 31;
            uint2 st = {cvtpk(acc[mt][nt][0] * sc, acc[mt][nt][1] * sc),
                        cvtpk(acc[mt][nt][2] * sc, acc[mt][nt][3] * sc)};
            *(uint2*)&ob[(((size_t)bb * 8 + hh) * 300 + nn) * 32 + dd] = st;
        }
    }
}

// ---------------- K3: fused attention, PAIR-PACKED PV, pipelined ----------------
__global__ __launch_bounds__(256, 3) void attn_mfma(
    const ushort* __restrict__ qg, const ushort* __restrict__ kg,
    const ushort* __restrict__ vg, const ushort* __restrict__ gpos,
    const float* __restrict__ gating, ushort* __restrict__ ot)
{
    __shared__ ushort Ks[304 * 40];    // [seq][k] stride 40 (80B)
    __shared__ ushort Vt[32 * 328];    // [dim][seq] stride 328, seq 300..327 zero

    int bh = blockIdx.x, b = bh >> 3, h = bh & 7;
    int tid = threadIdx.x, wave = tid >> 6, lane = tid & 63, li = lane & 15, qd = lane >> 4;
    const ushort* kb = kg + (size_t)bh * 9600;
    const ushort* vb = vg + (size_t)bh * 9600;

    for (int c = tid; c < 1200; c += 256) {        // K: 300 rows x 4 u8-chunks
        int r = c >> 2, k8 = (c & 3) * 8;
        *(uint4*)&Ks[r * 40 + k8] = *(const uint4*)(kb + r * 32 + k8);
    }
    for (int c = tid; c < 2400; c += 256) {        // V transpose: 300 x 8 u4-chunks
        int sq = c >> 3, d4 = (c & 7) * 4;
        ushort4 t = *(const ushort4*)(vb + sq * 32 + d4);
        Vt[(d4 + 0) * 328 + sq] = t.x;
        Vt[(d4 + 1) * 328 + sq] = t.y;
        Vt[(d4 + 2) * 328 + sq] = t.z;
        Vt[(d4 + 3) * 328 + sq] = t.w;
    }
    for (int c = tid; c < 896; c += 256) {         // Vt seq pad 300..327 -> 0
        int d = c & 31, s = c >> 5;
        Vt[d * 328 + 300 + s] = 0;
    }
    float g = 1.f / (1.f + __expf(-gating[h]));
    float omg = 1.f - g;
    __syncthreads();

    const ushort* ksp0 = &Ks[li * 40 + qd * 8];
    const ushort* vtp0 = &Vt[li * 328 + qd * 4];
    const ushort* vtp1 = &Vt[(16 + li) * 328 + qd * 4];
    const v4f z4 = {0.f, 0.f, 0.f, 0.f};

    for (int rg = wave; rg < 19; rg += 4) {
        int i0 = rg * 16;
        // Q as B-operand: lane li holds Q row (i0+li); rows>=300 read adjacent
        // valid memory (finite), masked at store
        v8s bq = *(const v8s*)(qg + (size_t)bh * 9600 + (i0 + li) * 32 + qd * 8);
        const ushort* gp = gpos + ((size_t)h * 304 + (i0 + li)) * 304 + qd * 4;

        v4f Oe0 = z4, Oe1 = z4, Og0 = z4, Og1 = z4;
        float esum = 0.f;

        // prologue: load pair 0 (tiles 0,1) operands + compute its scores
        v8s ak0 = *(const v8s*)(ksp0);
        v8s ak1 = *(const v8s*)(ksp0 + 640);
        uint2 v0a = *(const uint2*)(vtp0);
        uint2 v0b = *(const uint2*)(vtp0 + 16);
        uint2 v1a = *(const uint2*)(vtp1);
        uint2 v1b = *(const uint2*)(vtp1 + 16);
        uint2 g0 = *(const uint2*)(gp);
        uint2 g1 = *(const uint2*)(gp + 16);
        v4f s0n = __builtin_amdgcn_mfma_f32_16x16x32_bf16(ak0, bq, z4, 0, 0, 0);
        v4f s1n = __builtin_amdgcn_mfma_f32_16x16x32_bf16(ak1, bq, z4, 0, 0, 0);

#pragma unroll 1
        for (int p = 0; p < 9; ++p) {              // pairs (nt=2p, 2p+1), nt<=17
            v4f s0 = s0n, s1 = s1n;
            // full-K B operands: slots 0-3 = tile 2p, slots 4-7 = tile 2p+1
            v8s b0 = __builtin_bit_cast(v8s, (v4u){v0a.x, v0a.y, v0b.x, v0b.y});
            v8s b1 = __builtin_bit_cast(v8s, (v4u){v1a.x, v1a.y, v1b.x, v1b.y});
            v8s ag = __builtin_bit_cast(v8s, (v4u){g0.x, g0.y, g1.x, g1.y});
            int nt0 = 2 * p + 2;                   // next pair (p=8 -> tail tile 18)
            int nt1 = (p < 8) ? nt0 + 1 : 18;
            ak0 = *(const v8s*)(ksp0 + nt0 * 640);
            ak1 = *(const v8s*)(ksp0 + nt1 * 640);
            v0a = *(const uint2*)(vtp0 + nt0 * 16);
            v0b = *(const uint2*)(vtp0 + nt1 * 16);
            v1a = *(const uint2*)(vtp1 + nt0 * 16);
            v1b = *(const uint2*)(vtp1 + nt1 * 16);
            g0 = *(const uint2*)(gp + nt0 * 16);
            g1 = *(const uint2*)(gp + nt1 * 16);
            s0n = __builtin_amdgcn_mfma_f32_16x16x32_bf16(ak0, bq, z4, 0, 0, 0);
            s1n = __builtin_amdgcn_mfma_f32_16x16x32_bf16(ak1, bq, z4, 0, 0, 0);

            float e0 = fexp2(s0[0]);               // log2(e) folded into q scale
            float e1 = fexp2(s0[1]);
            float e2 = fexp2(s0[2]);
            float e3 = fexp2(s0[3]);
            float f0 = fexp2(s1[0]);
            float f1 = fexp2(s1[1]);
            float f2 = fexp2(s1[2]);
            float f3 = fexp2(s1[3]);
            esum += ((e0 + e1) + (e2 + e3)) + ((f0 + f1) + (f2 + f3));
            v8s ae = __builtin_bit_cast(v8s, (v4u){cvtpk(e0, e1), cvtpk(e2, e3),
                                                   cvtpk(f0, f1), cvtpk(f2, f3)});
            Oe0 = __builtin_amdgcn_mfma_f32_16x16x32_bf16(ae, b0, Oe0, 0, 0, 0);
            Oe1 = __builtin_amdgcn_mfma_f32_16x16x32_bf16(ae, b1, Oe1, 0, 0, 0);
            Og0 = __builtin_amdgcn_mfma_f32_16x16x32_bf16(ag, b0, Og0, 0, 0, 0);
            Og1 = __builtin_amdgcn_mfma_f32_16x16x32_bf16(ag, b1, Og1, 0, 0, 0);
        }
        {   // tail tile nt=18 (j=288..303): scores in s0n, operands in *a/g0 regs
            float e0 = fexp2(s0n[0]);
            float e1 = fexp2(s0n[1]);
            float e2 = fexp2(s0n[2]);
            float e3 = fexp2(s0n[3]);
            if (qd == 3) { e0 = e1 = e2 = e3 = 0.f; }   // j >= 300
            esum += (e0 + e1) + (e2 + e3);
            v8s ae = __builtin_bit_cast(v8s, (v4u){cvtpk(e0, e1), cvtpk(e2, e3), 0u, 0u});
            v8s ag = __builtin_bit_cast(v8s, (v4u){g0.x, g0.y, 0u, 0u});
            v8s b0 = __builtin_bit_cast(v8s, (v4u){v0a.x, v0a.y, 0u, 0u});
            v8s b1 = __builtin_bit_cast(v8s, (v4u){v1a.x, v1a.y, 0u, 0u});
            Oe0 = __builtin_amdgcn_mfma_f32_16x16x32_bf16(ae, b0, Oe0, 0, 0, 0);
            Oe1 = __builtin_amdgcn_mfma_f32_16x16x32_bf16(ae, b1, Oe1, 0, 0, 0);
            Og0 = __builtin_amdgcn_mfma_f32_16x16x32_bf16(ag, b0, Og0, 0, 0, 0);
            Og1 = __builtin_amdgcn_mfma_f32_16x16x32_bf16(ag, b1, Og1, 0, 0, 0);
        }
        esum += __shfl_xor(esum, 16);
        esum += __shfl_xor(esum, 32);              // full row sum for query i0+li
        float ps = omg / esum;                     // (skip /attn.sum: it's 1 +- 1e-6)
        float psr[4];
#pragma unroll
        for (int r = 0; r < 4; ++r) psr[r] = __shfl(ps, qd * 4 + r);
#pragma unroll
        for (int r = 0; r < 4; ++r) {
            int row = i0 + qd * 4 + r;
            if (row < NSEQ) {
                int m = b * NSEQ + row;
                int rt = m >> 7, rr = m & 127;
                int c0 = (h & 1) * 4 + (li >> 3);
                int p2 = li & 7;
                size_t tb = ((size_t)(rt * 4 + (h >> 1)) * 128 + rr) * 64;
                ot[tb + ((c0 ^ (rr & 7)) * 8) + p2] = f2bf(fmaf(psr[r], Oe0[r], Og0[r]));
                ot[tb + (((c0 + 2) ^ (rr & 7)) * 8) + p2] = f2bf(fmaf(psr[r], Oe1[r], Og1[r]));
            }
        }
    }
}

// ---------------- K4: output projection, swapped-operand MFMA, float4 stores ----------------
__global__ __launch_bounds__(256, 4) void gemm_proj_mfma(
    const ushort* __restrict__ A, const ushort* __restrict__ Bw,
    const float* __restrict__ bias, float* __restrict__ out)
{
    __shared__ ushort As[64 * 64];    // 8 KB
    __shared__ ushort Bs[128 * 64];   // 16 KB
    int tid = threadIdx.x;
    int wave = tid >> 6, lane = tid & 63, li = lane & 15, qd = lane >> 4;
    int rh = wave >> 1, ch = wave & 1;
    int by = blockIdx.y;
    const ushort* gA = A + ((size_t)(by >> 1) * 4 * 128 + (by & 1) * 64) * 64;
    const ushort* gB = Bw + (size_t)blockIdx.x * 4 * 8192;

    v4f acc[2][4];
#pragma unroll
    for (int i = 0; i < 2; ++i)
#pragma unroll
        for (int j = 0; j < 4; ++j) acc[i][j] = (v4f){0.f, 0.f, 0.f, 0.f};

    for (int kt = 0; kt < 4; ++kt) {
#pragma unroll
        for (int s = 0; s < 2; ++s) {
            int cch = s * 256 + tid;
            gl_lds16(gA + (size_t)kt * 128 * 64 + cch * 8, As + cch * 8);
        }
#pragma unroll
        for (int s = 0; s < 4; ++s) {
            int cch = s * 256 + tid;
            gl_lds16(gB + (size_t)kt * 8192 + cch * 8, Bs + cch * 8);
        }
        __syncthreads();
#pragma unroll
        for (int kc = 0; kc < 64; kc += 32) {
            int cb = (kc >> 3) + qd;
            int cs = cb ^ (li & 7);
            v8s a[2], b[4];
#pragma unroll
            for (int mt = 0; mt < 2; ++mt)
                a[mt] = *(const v8s*)&As[(rh * 32 + mt * 16 + li) * 64 + cs * 8];
#pragma unroll
            for (int nt = 0; nt < 4; ++nt)
                b[nt] = *(const v8s*)&Bs[(ch * 64 + nt * 16 + li) * 64 + cs * 8];
#pragma unroll
            for (int mt = 0; mt < 2; ++mt)
#pragma unroll
                for (int nt = 0; nt < 4; ++nt)
                    acc[mt][nt] = __builtin_amdgcn_mfma_f32_16x16x32_bf16(b[nt], a[mt], acc[mt][nt], 0, 0, 0);
        }
        __syncthreads();
    }

#pragma unroll
    for (int mt = 0; mt < 2; ++mt) {
        int row = by * 64 + rh * 32 + mt * 16 + li;
#pragma unroll
        for (int nt = 0; nt < 4; ++nt) {
            int col = blockIdx.x * 128 + ch * 64 + nt * 16 + qd * 4;
            float4 bv = *(const float4*)&bias[col];
            float4 st = {acc[mt][nt][0] + bv.x, acc[mt][nt][1] + bv.y,
                         acc[mt][nt][2] + bv.z, acc[mt][nt][3] + bv.w};
            *(float4*)&out[(size_t)row * 256 + col] = st;
        }
    }
}

extern "C" void kernel_launch(void* const* d_in, const int* in_sizes, int n_in,
                              void* d_out, int out_size, void* d_ws, size_t ws_size,
                              hipStream_t stream) {
    const float* x      = (const float*)d_in[0];
    const float* Wqk    = (const float*)d_in[1];
    const float* Wv     = (const float*)d_in[2];
    const float* Wpos   = (const float*)d_in[3];
    const float* bpos   = (const float*)d_in[4];
    const float* Wproj  = (const float*)d_in[5];
    const float* bproj  = (const float*)d_in[6];
    const float* gating = (const float*)d_in[7];
    float* out = (float*)d_out;

    ushort* gpos     = (ushort*)d_ws;             // 8*304*304 = 739,328
    ushort* x_t      = gpos + 739328;             // 4,915,200 (tiled+swizzled)
    ushort* wqkv_t   = x_t + 4915200;             // 196,608  (tiled+swizzled)
    ushort* wproj_t  = wqkv_t + 196608;           // 65,536   (tiled+swizzled)
    ushort* q_bf     = wproj_t + 65536;           // 4,915,200 each, [B,H,300,32]
    ushort* k_bf     = q_bf + 4915200;
    ushort* v_bf     = k_bf + 4915200;
    ushort* o_t      = v_bf + 4915200;            // 4,915,200 (tiled+swizzled)

    prep_kernel<<<3136, 256, 0, stream>>>(x, Wqk, Wv, Wproj, Wpos, bpos, gating,
                                          x_t, wqkv_t, wproj_t, gpos);
    gemm_qkv_mfma<<<dim3(6, 150), 256, 0, stream>>>(x_t, wqkv_t, q_bf, k_bf, v_bf);
    attn_mfma<<<dim3(64 * HEADS), 256, 0, stream>>>(q_bf, k_bf, v_bf, gpos, gating, o_t);
    gemm_proj_mfma<<<dim3(2, 300), 256, 0, stream>>>(o_t, wproj_t, bproj, out);
}

// Round 2
// 132.701 us; speedup vs baseline: 1.1515x; 1.1465x over previous
//
#include <hip/hip_runtime.h>

// GPSA bf16-MFMA v10. B=64, N=300, C=256, H=8, hd=32.
// STRUCTURAL: 4 kernels -> 3; q/k/v never hit HBM; x_t eliminated.
// K0 prep: gpos[h,i,j] = bf16(g_h*softmax_j(...)) [8,304,304];
//          Wf[h][kt][96][64] = [Wq_h|Wk_h|Wv_h] rows pre-swizzled for LDS DMA;
//          wproj_t tiled+swizzled (unchanged).
// K23 fused_qkv_attn: per (b,h) block: GEMM phase computes q/k/v[304x32] from
//          raw fp32 x[b] (reg-converted to bf16 into swizzled LDS) with 16x16x32
//          MFMA (acc 5x6 v4f), writes q/k/v into attention-layout LDS (Qs/Ks row-
//          major stride 40, Vt transposed stride 328, rows 300..303 exact zeros
//          from zero-padded X); attention phase = v9's pair-packed loop (exp2,
//          cvt_pk, gpos 2-deep global prefetch). Grid id = h*64+b so the 8
//          h-blocks of one b share an XCD -> x[b] L2-resident.
// K4 gemm_proj_mfma: unchanged (DMA staging, swapped operands, float4 stores).

#define NSEQ 300
#define HEADS 8
#define HD 32

typedef short v8s __attribute__((ext_vector_type(8)));
typedef float v4f __attribute__((ext_vector_type(4)));
typedef unsigned int v4u __attribute__((ext_vector_type(4)));

__device__ __forceinline__ ushort f2bf(float f) {
    unsigned u = __float_as_uint(f);
    u = (u + 0x7FFFu + ((u >> 16) & 1u)) >> 16;   // RNE
    return (ushort)u;
}

// pack two fp32 -> packed bf16x2 (lo=a, hi=b) via v_perm
__device__ __forceinline__ unsigned pk2bf(float a, float b) {
    unsigned ua = __float_as_uint(a), ub = __float_as_uint(b);
    ua += 0x7FFFu + ((ua >> 16) & 1u);
    ub += 0x7FFFu + ((ub >> 16) & 1u);
    return __builtin_amdgcn_perm(ub, ua, 0x07060302);  // [ua.hi16 | ub.hi16]
}

// single-instruction RNE pack (lo=a, hi=b)
__device__ __forceinline__ unsigned cvtpk(float a, float b) {
    unsigned r;
    asm("v_cvt_pk_bf16_f32 %0, %1, %2" : "=v"(r) : "v"(a), "v"(b));
    return r;
}

__device__ __forceinline__ float fexp2(float x) {
    float r; asm("v_exp_f32 %0, %1" : "=v"(r) : "v"(x)); return r;
}

// async global->LDS DMA, 16B per lane
__device__ __forceinline__ void gl_lds16(const ushort* g, ushort* l) {
    __builtin_amdgcn_global_load_lds(
        (const __attribute__((address_space(1))) void*)g,
        (__attribute__((address_space(3))) void*)l, 16, 0, 0);
}

// ---------------- K0: prep = gpos softmax + weight swizzle ----------------
// blocks 0..607: gpos rows | 608..703: Wf (qkv weights) | 704..735: wproj_t
__global__ __launch_bounds__(256) void prep_kernel(
    const float* __restrict__ Wqk, const float* __restrict__ Wv,
    const float* __restrict__ Wproj, const float* __restrict__ Wpos,
    const float* __restrict__ bpos, const float* __restrict__ gating,
    ushort* __restrict__ Wf, ushort* __restrict__ wproj_t,
    ushort* __restrict__ gpos)
{
    int bid = blockIdx.x, tid = threadIdx.x;
    if (bid < 608) {                            // gated positional softmax
        int sub = bid;
        int h = sub / 76;
        int i = (sub % 76) * 4 + (tid >> 6);    // row 0..303
        int lane = tid & 63;
        ushort* gr = gpos + ((size_t)h * 304 + i) * 304;
        if (i >= NSEQ) {
#pragma unroll
            for (int t = 0; t < 5; ++t) {
                int j = lane + 64 * t;
                if (j < 304) gr[j] = 0;
            }
            return;
        }
        float w0 = Wpos[h * 3 + 0], w2 = Wpos[h * 3 + 2], bb = bpos[h];
        float g = 1.f / (1.f + __expf(-gating[h]));
        float sv[5]; float m2 = -1e30f;
#pragma unroll
        for (int t = 0; t < 5; ++t) {
            int j = lane + 64 * t;
            float d = (float)(j - i);
            float lg = fmaf(w2, d * d, fmaf(w0, d, bb));
            sv[t] = (j < NSEQ) ? lg : -1e30f;   // logits +-7000: max-sub required
            m2 = fmaxf(m2, sv[t]);
        }
#pragma unroll
        for (int off = 32; off > 0; off >>= 1) m2 = fmaxf(m2, __shfl_xor(m2, off));
        float sum = 0.f;
#pragma unroll
        for (int t = 0; t < 5; ++t) { sv[t] = __expf(sv[t] - m2); sum += sv[t]; }
#pragma unroll
        for (int off = 32; off > 0; off >>= 1) sum += __shfl_xor(sum, off);
        float gi = g / sum;
#pragma unroll
        for (int t = 0; t < 5; ++t) {
            int j = lane + 64 * t;
            if (j < NSEQ) gr[j] = f2bf(sv[t] * gi);
            else if (j < 304) gr[j] = 0;
        }
        return;
    }
    if (bid < 704) {                            // Wf: 8h x 4kt x 96 rows x 8 chunks
        int idx = (bid - 608) * 256 + tid;      // 0..24575
        int c = idx & 7;
        int t = idx >> 3;                       // 0..3071
        int hk = t / 96;                        // h*4+kt
        int wc = t - hk * 96;                   // 0..95
        int h = hk >> 2, kt = hk & 3;
        const float* src;
        if (wc < 32)      src = Wqk + (size_t)(h * 32 + wc) * 256;
        else if (wc < 64) src = Wqk + (size_t)(256 + h * 32 + (wc - 32)) * 256;
        else              src = Wv + (size_t)(h * 32 + (wc - 64)) * 256;
        src += kt * 64 + c * 8;
        float4 f0 = *(const float4*)src;
        float4 f1 = *(const float4*)(src + 4);
        v4u pk = {pk2bf(f0.x, f0.y), pk2bf(f0.z, f0.w),
                  pk2bf(f1.x, f1.y), pk2bf(f1.z, f1.w)};
        *(v4u*)&Wf[((size_t)(hk * 96 + wc)) * 64 + ((c ^ (wc & 7)) * 8)] = pk;
        return;
    }
    {                                           // wproj_t: 256 rows x 32 chunks
        int idx = (bid - 704) * 256 + tid;      // 0..8191
        int m = idx >> 5, ck = idx & 31;
        const float* src = Wproj + (size_t)m * 256 + ck * 8;
        int rt = m >> 7, rr = m & 127, kt = ck >> 3, c = ck & 7;
        float4 f0 = *(const float4*)src;
        float4 f1 = *(const float4*)(src + 4);
        v4u pk = {pk2bf(f0.x, f0.y), pk2bf(f0.z, f0.w),
                  pk2bf(f1.x, f1.y), pk2bf(f1.z, f1.w)};
        *(v4u*)&wproj_t[((size_t)(rt * 4 + kt) * 128 + rr) * 64 + ((c ^ (rr & 7)) * 8)] = pk;
    }
}

// ---------------- K23: fused QKV GEMM + attention ----------------
// block = (b,h) with id = h*64 + b  (same-b blocks share XCD -> x[b] L2-local)
__global__ __launch_bounds__(256, 2) void fused_qkv_attn(
    const float* __restrict__ x, const ushort* __restrict__ Wf,
    const ushort* __restrict__ gpos, const float* __restrict__ gating,
    ushort* __restrict__ ot)
{
    __shared__ ushort smem[34816];     // 69632 B
    ushort* Xs = smem;                 // GEMM: [304][64] swizzled (38912 B)
    ushort* Wsh = smem + 19456;        // GEMM: [96][64] swizzled (12288 B)
    ushort* Qs = smem;                 // ATTN: [304][40] (24320 B)
    ushort* Ks = smem + 12160;         // ATTN: [304][40]
    ushort* Vt = smem + 24320;         // ATTN: [32][328]

    int bid = blockIdx.x, b = bid & 63, h = bid >> 6;
    int tid = threadIdx.x, wave = tid >> 6, lane = tid & 63, li = lane & 15, qd = lane >> 4;

    const float* xb = x + (size_t)b * 300 * 256;
    const ushort* wfh = Wf + (size_t)h * 4 * 6144;

    v4f acc[5][6];
#pragma unroll
    for (int i = 0; i < 5; ++i)
#pragma unroll
        for (int j = 0; j < 6; ++j) acc[i][j] = (v4f){0.f, 0.f, 0.f, 0.f};

    // -------- GEMM phase: q|k|v[304x96] = X[304x256] @ W[256x96] --------
    for (int kt = 0; kt < 4; ++kt) {
#pragma unroll
        for (int s = 0; s < 3; ++s) {          // Ws: 768 DMA chunks of 16B
            int c = s * 256 + tid;
            gl_lds16(wfh + (size_t)kt * 6144 + c * 8, Wsh + c * 8);
        }
#pragma unroll
        for (int it = 0; it < 19; ++it) {      // Xs: 4864 float4 = 304 rows x 16
            int c = it * 256 + tid;
            int r = c >> 4, q4 = c & 15;
            float4 f = {0.f, 0.f, 0.f, 0.f};
            if (r < 300) f = *(const float4*)(xb + (size_t)r * 256 + kt * 64 + q4 * 4);
            uint2 w = {cvtpk(f.x, f.y), cvtpk(f.z, f.w)};
            *(uint2*)&Xs[r * 64 + (((q4 >> 1) ^ (r & 7)) * 8) + (q4 & 1) * 4] = w;
        }
        __syncthreads();
#pragma unroll
        for (int kc = 0; kc < 64; kc += 32) {
            int cb = (kc >> 3) + qd;
            int cs = cb ^ (li & 7);
            v8s bw[6];
#pragma unroll
            for (int ct = 0; ct < 6; ++ct)
                bw[ct] = *(const v8s*)&Wsh[(ct * 16 + li) * 64 + cs * 8];
#pragma unroll
            for (int i = 0; i < 5; ++i) {
                int rt = wave + i * 4;
                if (rt < 19) {
                    v8s ax = *(const v8s*)&Xs[(rt * 16 + li) * 64 + cs * 8];
#pragma unroll
                    for (int ct = 0; ct < 6; ++ct)
                        acc[i][ct] = __builtin_amdgcn_mfma_f32_16x16x32_bf16(bw[ct], ax, acc[i][ct], 0, 0, 0);
                }
            }
        }
        __syncthreads();
    }

    // -------- writeback q/k/v into attention-layout LDS --------
    // swapped-operand acc: C[row = rt*16+li][col = ct*16 + qd*4 + r]
    const float QSC = 0.25503486063f;          // log2(e)/sqrt(32)
#pragma unroll
    for (int i = 0; i < 5; ++i) {
        int rt = wave + i * 4;
        if (rt < 19) {
            int row = rt * 16 + li;
#pragma unroll
            for (int ct = 0; ct < 2; ++ct) {   // q -> Qs[row][dim]
                uint2 wq = {cvtpk(acc[i][ct][0] * QSC, acc[i][ct][1] * QSC),
                            cvtpk(acc[i][ct][2] * QSC, acc[i][ct][3] * QSC)};
                *(uint2*)&Qs[row * 40 + ct * 16 + qd * 4] = wq;
            }
#pragma unroll
            for (int ct = 2; ct < 4; ++ct) {   // k -> Ks[row][dim]
                uint2 wk = {cvtpk(acc[i][ct][0], acc[i][ct][1]),
                            cvtpk(acc[i][ct][2], acc[i][ct][3])};
                *(uint2*)&Ks[row * 40 + (ct - 2) * 16 + qd * 4] = wk;
            }
#pragma unroll
            for (int ct = 4; ct < 6; ++ct)     // v -> Vt[dim][row] (transposed)
#pragma unroll
                for (int r = 0; r < 4; ++r)
                    Vt[((ct - 4) * 16 + qd * 4 + r) * 328 + row] = f2bf(acc[i][ct][r]);
        }
    }
    float g = 1.f / (1.f + __expf(-gating[h]));
    float omg = 1.f - g;
    __syncthreads();

    // -------- attention phase (v9 pair-packed loop) --------
    const ushort* ksp0 = &Ks[li * 40 + qd * 8];
    const ushort* vtp0 = &Vt[li * 328 + qd * 4];
    const ushort* vtp1 = &Vt[(16 + li) * 328 + qd * 4];
    const v4f z4 = {0.f, 0.f, 0.f, 0.f};

    for (int rg = wave; rg < 19; rg += 4) {
        int i0 = rg * 16;
        // Q rows >= 300 are exact zeros (zero-padded X) -> masked at store
        v8s bq = *(const v8s*)&Qs[(i0 + li) * 40 + qd * 8];
        const ushort* gp = gpos + ((size_t)h * 304 + (i0 + li)) * 304 + qd * 4;

        v4f Oe0 = z4, Oe1 = z4, Og0 = z4, Og1 = z4;
        float esum = 0.f;

        // prologue: load pair 0 (tiles 0,1) operands + compute its scores
        v8s ak0 = *(const v8s*)(ksp0);
        v8s ak1 = *(const v8s*)(ksp0 + 640);
        uint2 v0a = *(const uint2*)(vtp0);
        uint2 v0b = *(const uint2*)(vtp0 + 16);
        uint2 v1a = *(const uint2*)(vtp1);
        uint2 v1b = *(const uint2*)(vtp1 + 16);
        uint2 g0 = *(const uint2*)(gp);
        uint2 g1 = *(const uint2*)(gp + 16);
        v4f s0n = __builtin_amdgcn_mfma_f32_16x16x32_bf16(ak0, bq, z4, 0, 0, 0);
        v4f s1n = __builtin_amdgcn_mfma_f32_16x16x32_bf16(ak1, bq, z4, 0, 0, 0);

#pragma unroll 1
        for (int p = 0; p < 9; ++p) {          // pairs (nt=2p, 2p+1), nt<=17
            v4f s0 = s0n, s1 = s1n;
            v8s b0 = __builtin_bit_cast(v8s, (v4u){v0a.x, v0a.y, v0b.x, v0b.y});
            v8s b1 = __builtin_bit_cast(v8s, (v4u){v1a.x, v1a.y, v1b.x, v1b.y});
            v8s ag = __builtin_bit_cast(v8s, (v4u){g0.x, g0.y, g1.x, g1.y});
            int nt0 = 2 * p + 2;               // next pair (p=8 -> tail tile 18)
            int nt1 = (p < 8) ? nt0 + 1 : 18;
            ak0 = *(const v8s*)(ksp0 + nt0 * 640);
            ak1 = *(const v8s*)(ksp0 + nt1 * 640);
            v0a = *(const uint2*)(vtp0 + nt0 * 16);
            v0b = *(const uint2*)(vtp0 + nt1 * 16);
            v1a = *(const uint2*)(vtp1 + nt0 * 16);
            v1b = *(const uint2*)(vtp1 + nt1 * 16);
            g0 = *(const uint2*)(gp + nt0 * 16);
            g1 = *(const uint2*)(gp + nt1 * 16);
            s0n = __builtin_amdgcn_mfma_f32_16x16x32_bf16(ak0, bq, z4, 0, 0, 0);
            s1n = __builtin_amdgcn_mfma_f32_16x16x32_bf16(ak1, bq, z4, 0, 0, 0);

            float e0 = fexp2(s0[0]);           // log2(e) folded into q scale
            float e1 = fexp2(s0[1]);
            float e2 = fexp2(s0[2]);
            float e3 = fexp2(s0[3]);
            float f0 = fexp2(s1[0]);
            float f1 = fexp2(s1[1]);
            float f2 = fexp2(s1[2]);
            float f3 = fexp2(s1[3]);
            esum += ((e0 + e1) + (e2 + e3)) + ((f0 + f1) + (f2 + f3));
            v8s ae = __builtin_bit_cast(v8s, (v4u){cvtpk(e0, e1), cvtpk(e2, e3),
                                                   cvtpk(f0, f1), cvtpk(f2, f3)});
            Oe0 = __builtin_amdgcn_mfma_f32_16x16x32_bf16(ae, b0, Oe0, 0, 0, 0);
            Oe1 = __builtin_amdgcn_mfma_f32_16x16x32_bf16(ae, b1, Oe1, 0, 0, 0);
            Og0 = __builtin_amdgcn_mfma_f32_16x16x32_bf16(ag, b0, Og0, 0, 0, 0);
            Og1 = __builtin_amdgcn_mfma_f32_16x16x32_bf16(ag, b1, Og1, 0, 0, 0);
        }
        {   // tail tile nt=18 (j=288..303): scores in s0n, operands in regs
            float e0 = fexp2(s0n[0]);
            float e1 = fexp2(s0n[1]);
            float e2 = fexp2(s0n[2]);
            float e3 = fexp2(s0n[3]);
            if (qd == 3) { e0 = e1 = e2 = e3 = 0.f; }   // j >= 300
            esum += (e0 + e1) + (e2 + e3);
            v8s ae = __builtin_bit_cast(v8s, (v4u){cvtpk(e0, e1), cvtpk(e2, e3), 0u, 0u});
            v8s ag = __builtin_bit_cast(v8s, (v4u){g0.x, g0.y, 0u, 0u});
            v8s b0 = __builtin_bit_cast(v8s, (v4u){v0a.x, v0a.y, 0u, 0u});
            v8s b1 = __builtin_bit_cast(v8s, (v4u){v1a.x, v1a.y, 0u, 0u});
            Oe0 = __builtin_amdgcn_mfma_f32_16x16x32_bf16(ae, b0, Oe0, 0, 0, 0);
            Oe1 = __builtin_amdgcn_mfma_f32_16x16x32_bf16(ae, b1, Oe1, 0, 0, 0);
            Og0 = __builtin_amdgcn_mfma_f32_16x16x32_bf16(ag, b0, Og0, 0, 0, 0);
            Og1 = __builtin_amdgcn_mfma_f32_16x16x32_bf16(ag, b1, Og1, 0, 0, 0);
        }
        esum += __shfl_xor(esum, 16);
        esum += __shfl_xor(esum, 32);          // full row sum for query i0+li
        float ps = omg / esum;                 // (skip /attn.sum: it's 1 +- 1e-6)
        float psr[4];
#pragma unroll
        for (int r = 0; r < 4; ++r) psr[r] = __shfl(ps, qd * 4 + r);
#pragma unroll
        for (int r = 0; r < 4; ++r) {
            int row = i0 + qd * 4 + r;
            if (row < NSEQ) {
                int m = b * NSEQ + row;
                int rt = m >> 7, rr = m & 127;
                int c0 = (h & 1) * 4 + (li >> 3);
                int p2 = li & 7;
                size_t tb = ((size_t)(rt * 4 + (h >> 1)) * 128 + rr) * 64;
                ot[tb + ((c0 ^ (rr & 7)) * 8) + p2] = f2bf(fmaf(psr[r], Oe0[r], Og0[r]));
                ot[tb + (((c0 + 2) ^ (rr & 7)) * 8) + p2] = f2bf(fmaf(psr[r], Oe1[r], Og1[r]));
            }
        }
    }
}

// ---------------- K4: output projection, BM=64, DMA staging + bias ----------------
__global__ __launch_bounds__(256, 4) void gemm_proj_mfma(
    const ushort* __restrict__ A, const ushort* __restrict__ Bw,
    const float* __restrict__ bias, float* __restrict__ out)
{
    __shared__ ushort As[64 * 64];    // 8 KB
    __shared__ ushort Bs[128 * 64];   // 16 KB
    int tid = threadIdx.x;
    int wave = tid >> 6, lane = tid & 63, li = lane & 15, qd = lane >> 4;
    int rh = wave >> 1, ch = wave & 1;
    int by = blockIdx.y;
    const ushort* gA = A + ((size_t)(by >> 1) * 4 * 128 + (by & 1) * 64) * 64;
    const ushort* gB = Bw + (size_t)blockIdx.x * 4 * 8192;

    v4f acc[2][4];
#pragma unroll
    for (int i = 0; i < 2; ++i)
#pragma unroll
        for (int j = 0; j < 4; ++j) acc[i][j] = (v4f){0.f, 0.f, 0.f, 0.f};

    for (int kt = 0; kt < 4; ++kt) {
#pragma unroll
        for (int s = 0; s < 2; ++s) {
            int cch = s * 256 + tid;
            gl_lds16(gA + (size_t)kt * 128 * 64 + cch * 8, As + cch * 8);
        }
#pragma unroll
        for (int s = 0; s < 4; ++s) {
            int cch = s * 256 + tid;
            gl_lds16(gB + (size_t)kt * 8192 + cch * 8, Bs + cch * 8);
        }
        __syncthreads();
#pragma unroll
        for (int kc = 0; kc < 64; kc += 32) {
            int cb = (kc >> 3) + qd;
            int cs = cb ^ (li & 7);
            v8s a[2], b[4];
#pragma unroll
            for (int mt = 0; mt < 2; ++mt)
                a[mt] = *(const v8s*)&As[(rh * 32 + mt * 16 + li) * 64 + cs * 8];
#pragma unroll
            for (int nt = 0; nt < 4; ++nt)
                b[nt] = *(const v8s*)&Bs[(ch * 64 + nt * 16 + li) * 64 + cs * 8];
#pragma unroll
            for (int mt = 0; mt < 2; ++mt)
#pragma unroll
                for (int nt = 0; nt < 4; ++nt)
                    acc[mt][nt] = __builtin_amdgcn_mfma_f32_16x16x32_bf16(b[nt], a[mt], acc[mt][nt], 0, 0, 0);
        }
        __syncthreads();
    }

#pragma unroll
    for (int mt = 0; mt < 2; ++mt) {
        int row = by * 64 + rh * 32 + mt * 16 + li;
#pragma unroll
        for (int nt = 0; nt < 4; ++nt) {
            int col = blockIdx.x * 128 + ch * 64 + nt * 16 + qd * 4;
            float4 bv = *(const float4*)&bias[col];
            float4 st = {acc[mt][nt][0] + bv.x, acc[mt][nt][1] + bv.y,
                         acc[mt][nt][2] + bv.z, acc[mt][nt][3] + bv.w};
            *(float4*)&out[(size_t)row * 256 + col] = st;
        }
    }
}

extern "C" void kernel_launch(void* const* d_in, const int* in_sizes, int n_in,
                              void* d_out, int out_size, void* d_ws, size_t ws_size,
                              hipStream_t stream) {
    const float* x      = (const float*)d_in[0];
    const float* Wqk    = (const float*)d_in[1];
    const float* Wv     = (const float*)d_in[2];
    const float* Wpos   = (const float*)d_in[3];
    const float* bpos   = (const float*)d_in[4];
    const float* Wproj  = (const float*)d_in[5];
    const float* bproj  = (const float*)d_in[6];
    const float* gating = (const float*)d_in[7];
    float* out = (float*)d_out;

    ushort* gpos     = (ushort*)d_ws;             // 8*304*304 = 739,328
    ushort* Wf       = gpos + 739328;             // 8*4*96*64 = 196,608 (swizzled)
    ushort* wproj_t  = Wf + 196608;               // 65,536 (tiled+swizzled)
    ushort* o_t      = wproj_t + 65536;           // 4,915,200 (tiled+swizzled)

    prep_kernel<<<736, 256, 0, stream>>>(Wqk, Wv, Wproj, Wpos, bpos, gating,
                                         Wf, wproj_t, gpos);
    fused_qkv_attn<<<512, 256, 0, stream>>>(x, Wf, gpos, gating, o_t);
    gemm_proj_mfma<<<dim3(2, 300), 256, 0, stream>>>(o_t, wproj_t, bproj, out);
}

// Round 3
// 124.046 us; speedup vs baseline: 1.2318x; 1.0698x over previous
//
#include <hip/hip_runtime.h>

// GPSA bf16-MFMA v11. B=64, N=300, C=256, H=8, hd=32.
// v10 -> v11: X staging in the fused kernel moves from VGPR-choked
// load+cvt+ds_write (VGPR=128 left ~2 loads in flight -> serial HBM latency)
// to global_load_lds DMA of a pre-converted bf16 x_bf, with the LDS swizzle
// applied on the per-lane GLOBAL source address (LDS dest linear).
// K0 prep: x -> x_bf [64][304][256] bf16 row-major (rows 300..303 zero);
//          gpos[h,i,j] = bf16(g_h*softmax_j(...)) [8,304,304];
//          Wf[h][kt][96][64] pre-swizzled; wproj_t tiled+swizzled.
// K23 fused_qkv_attn: GEMM phase all-DMA staging (X + W), then v10's
//          writeback + pair-packed attention loop (+ s_setprio around PV MFMAs).
// K4 gemm_proj_mfma: unchanged.

#define NSEQ 300
#define HEADS 8
#define HD 32

typedef short v8s __attribute__((ext_vector_type(8)));
typedef float v4f __attribute__((ext_vector_type(4)));
typedef unsigned int v4u __attribute__((ext_vector_type(4)));

__device__ __forceinline__ ushort f2bf(float f) {
    unsigned u = __float_as_uint(f);
    u = (u + 0x7FFFu + ((u >> 16) & 1u)) >> 16;   // RNE
    return (ushort)u;
}

// pack two fp32 -> packed bf16x2 (lo=a, hi=b) via v_perm
__device__ __forceinline__ unsigned pk2bf(float a, float b) {
    unsigned ua = __float_as_uint(a), ub = __float_as_uint(b);
    ua += 0x7FFFu + ((ua >> 16) & 1u);
    ub += 0x7FFFu + ((ub >> 16) & 1u);
    return __builtin_amdgcn_perm(ub, ua, 0x07060302);  // [ua.hi16 | ub.hi16]
}

// single-instruction RNE pack (lo=a, hi=b)
__device__ __forceinline__ unsigned cvtpk(float a, float b) {
    unsigned r;
    asm("v_cvt_pk_bf16_f32 %0, %1, %2" : "=v"(r) : "v"(a), "v"(b));
    return r;
}

__device__ __forceinline__ float fexp2(float x) {
    float r; asm("v_exp_f32 %0, %1" : "=v"(r) : "v"(x)); return r;
}

// async global->LDS DMA, 16B per lane
__device__ __forceinline__ void gl_lds16(const ushort* g, ushort* l) {
    __builtin_amdgcn_global_load_lds(
        (const __attribute__((address_space(1))) void*)g,
        (__attribute__((address_space(3))) void*)l, 16, 0, 0);
}

// ---------------- K0: prep = x->bf16 + gpos softmax + weight swizzle ----------------
// blocks 0..2431: x_bf | 2432..3039: gpos | 3040..3135: Wf | 3136..3167: wproj_t
__global__ __launch_bounds__(256) void prep_kernel(
    const float* __restrict__ x,
    const float* __restrict__ Wqk, const float* __restrict__ Wv,
    const float* __restrict__ Wproj, const float* __restrict__ Wpos,
    const float* __restrict__ bpos, const float* __restrict__ gating,
    ushort* __restrict__ x_bf, ushort* __restrict__ Wf,
    ushort* __restrict__ wproj_t, ushort* __restrict__ gpos)
{
    int bid = blockIdx.x, tid = threadIdx.x;
    if (bid < 2432) {                           // x -> x_bf [64][304][256], zero-pad
        int idx = bid * 256 + tid;              // 0..622591
        int c8 = idx & 31;                      // 8-float chunk in row
        int mrow = idx >> 5;                    // b*304 + r
        unsigned b = (unsigned)mrow / 304u;
        int r = mrow - (int)b * 304;
        v4u pk = {0u, 0u, 0u, 0u};
        if (r < 300) {
            const float* src = x + ((size_t)b * 300 + r) * 256 + c8 * 8;
            float4 f0 = *(const float4*)src;
            float4 f1 = *(const float4*)(src + 4);
            pk = (v4u){pk2bf(f0.x, f0.y), pk2bf(f0.z, f0.w),
                       pk2bf(f1.x, f1.y), pk2bf(f1.z, f1.w)};
        }
        *(v4u*)&x_bf[(size_t)mrow * 256 + c8 * 8] = pk;
        return;
    }
    if (bid < 3040) {                           // gated positional softmax
        int sub = bid - 2432;
        int h = sub / 76;
        int i = (sub % 76) * 4 + (tid >> 6);    // row 0..303
        int lane = tid & 63;
        ushort* gr = gpos + ((size_t)h * 304 + i) * 304;
        if (i >= NSEQ) {
#pragma unroll
            for (int t = 0; t < 5; ++t) {
                int j = lane + 64 * t;
                if (j < 304) gr[j] = 0;
            }
            return;
        }
        float w0 = Wpos[h * 3 + 0], w2 = Wpos[h * 3 + 2], bb = bpos[h];
        float g = 1.f / (1.f + __expf(-gating[h]));
        float sv[5]; float m2 = -1e30f;
#pragma unroll
        for (int t = 0; t < 5; ++t) {
            int j = lane + 64 * t;
            float d = (float)(j - i);
            float lg = fmaf(w2, d * d, fmaf(w0, d, bb));
            sv[t] = (j < NSEQ) ? lg : -1e30f;   // logits +-7000: max-sub required
            m2 = fmaxf(m2, sv[t]);
        }
#pragma unroll
        for (int off = 32; off > 0; off >>= 1) m2 = fmaxf(m2, __shfl_xor(m2, off));
        float sum = 0.f;
#pragma unroll
        for (int t = 0; t < 5; ++t) { sv[t] = __expf(sv[t] - m2); sum += sv[t]; }
#pragma unroll
        for (int off = 32; off > 0; off >>= 1) sum += __shfl_xor(sum, off);
        float gi = g / sum;
#pragma unroll
        for (int t = 0; t < 5; ++t) {
            int j = lane + 64 * t;
            if (j < NSEQ) gr[j] = f2bf(sv[t] * gi);
            else if (j < 304) gr[j] = 0;
        }
        return;
    }
    if (bid < 3136) {                           // Wf: 8h x 4kt x 96 rows x 8 chunks
        int idx = (bid - 3040) * 256 + tid;     // 0..24575
        int c = idx & 7;
        int t = idx >> 3;                       // 0..3071
        int hk = t / 96;                        // h*4+kt
        int wc = t - hk * 96;                   // 0..95
        int h = hk >> 2, kt = hk & 3;
        const float* src;
        if (wc < 32)      src = Wqk + (size_t)(h * 32 + wc) * 256;
        else if (wc < 64) src = Wqk + (size_t)(256 + h * 32 + (wc - 32)) * 256;
        else              src = Wv + (size_t)(h * 32 + (wc - 64)) * 256;
        src += kt * 64 + c * 8;
        float4 f0 = *(const float4*)src;
        float4 f1 = *(const float4*)(src + 4);
        v4u pk = {pk2bf(f0.x, f0.y), pk2bf(f0.z, f0.w),
                  pk2bf(f1.x, f1.y), pk2bf(f1.z, f1.w)};
        *(v4u*)&Wf[((size_t)(hk * 96 + wc)) * 64 + ((c ^ (wc & 7)) * 8)] = pk;
        return;
    }
    {                                           // wproj_t: 256 rows x 32 chunks
        int idx = (bid - 3136) * 256 + tid;     // 0..8191
        int m = idx >> 5, ck = idx & 31;
        const float* src = Wproj + (size_t)m * 256 + ck * 8;
        int rt = m >> 7, rr = m & 127, kt = ck >> 3, c = ck & 7;
        float4 f0 = *(const float4*)src;
        float4 f1 = *(const float4*)(src + 4);
        v4u pk = {pk2bf(f0.x, f0.y), pk2bf(f0.z, f0.w),
                  pk2bf(f1.x, f1.y), pk2bf(f1.z, f1.w)};
        *(v4u*)&wproj_t[((size_t)(rt * 4 + kt) * 128 + rr) * 64 + ((c ^ (rr & 7)) * 8)] = pk;
    }
}

// ---------------- K23: fused QKV GEMM + attention ----------------
// block = (b,h) with id = h*64 + b  (consecutive blocks share h -> gpos L2-local)
__global__ __launch_bounds__(256, 2) void fused_qkv_attn(
    const ushort* __restrict__ x_bf, const ushort* __restrict__ Wf,
    const ushort* __restrict__ gpos, const float* __restrict__ gating,
    ushort* __restrict__ ot)
{
    __shared__ ushort smem[34816];     // 69632 B
    ushort* Xs = smem;                 // GEMM: [304][64] swizzled (38912 B)
    ushort* Wsh = smem + 19456;        // GEMM: [96][64] swizzled (12288 B)
    ushort* Qs = smem;                 // ATTN: [304][40] (24320 B)
    ushort* Ks = smem + 12160;         // ATTN: [304][40]
    ushort* Vt = smem + 24320;         // ATTN: [32][328]

    int bid = blockIdx.x, b = bid & 63, h = bid >> 6;
    int tid = threadIdx.x, wave = tid >> 6, lane = tid & 63, li = lane & 15, qd = lane >> 4;

    const ushort* xbb = x_bf + (size_t)b * 304 * 256;
    const ushort* wfh = Wf + (size_t)h * 4 * 6144;

    v4f acc[5][6];
#pragma unroll
    for (int i = 0; i < 5; ++i)
#pragma unroll
        for (int j = 0; j < 6; ++j) acc[i][j] = (v4f){0.f, 0.f, 0.f, 0.f};

    // -------- GEMM phase: q|k|v[304x96] = X[304x256] @ W[256x96] --------
    // All staging is global_load_lds DMA; the Xs swizzle is applied on the
    // per-lane GLOBAL source address (LDS dest stays linear).
    for (int kt = 0; kt < 4; ++kt) {
#pragma unroll
        for (int s = 0; s < 3; ++s) {          // Ws: 768 DMA chunks of 16B
            int c = s * 256 + tid;
            gl_lds16(wfh + (size_t)kt * 6144 + c * 8, Wsh + c * 8);
        }
#pragma unroll
        for (int s = 0; s < 9; ++s) {          // Xs: 2432 chunks (2304 here)
            int cch = s * 256 + tid;
            int r = cch >> 3, sl = cch & 7;
            gl_lds16(xbb + (size_t)r * 256 + kt * 64 + ((sl ^ (r & 7)) * 8),
                     Xs + cch * 8);
        }
        if (tid < 128) {                       // last 128 chunks
            int cch = 2304 + tid;
            int r = cch >> 3, sl = cch & 7;
            gl_lds16(xbb + (size_t)r * 256 + kt * 64 + ((sl ^ (r & 7)) * 8),
                     Xs + cch * 8);
        }
        __syncthreads();                       // drains vmcnt (DMA)
#pragma unroll
        for (int kc = 0; kc < 64; kc += 32) {
            int cb = (kc >> 3) + qd;
            int cs = cb ^ (li & 7);
            v8s bw[6];
#pragma unroll
            for (int ct = 0; ct < 6; ++ct)
                bw[ct] = *(const v8s*)&Wsh[(ct * 16 + li) * 64 + cs * 8];
#pragma unroll
            for (int i = 0; i < 5; ++i) {
                int rt = wave + i * 4;
                if (rt < 19) {
                    v8s ax = *(const v8s*)&Xs[(rt * 16 + li) * 64 + cs * 8];
#pragma unroll
                    for (int ct = 0; ct < 6; ++ct)
                        acc[i][ct] = __builtin_amdgcn_mfma_f32_16x16x32_bf16(bw[ct], ax, acc[i][ct], 0, 0, 0);
                }
            }
        }
        __syncthreads();
    }

    // -------- writeback q/k/v into attention-layout LDS --------
    // swapped-operand acc: C[row = rt*16+li][col = ct*16 + qd*4 + r]
    const float QSC = 0.25503486063f;          // log2(e)/sqrt(32)
#pragma unroll
    for (int i = 0; i < 5; ++i) {
        int rt = wave + i * 4;
        if (rt < 19) {
            int row = rt * 16 + li;
#pragma unroll
            for (int ct = 0; ct < 2; ++ct) {   // q -> Qs[row][dim]
                uint2 wq = {cvtpk(acc[i][ct][0] * QSC, acc[i][ct][1] * QSC),
                            cvtpk(acc[i][ct][2] * QSC, acc[i][ct][3] * QSC)};
                *(uint2*)&Qs[row * 40 + ct * 16 + qd * 4] = wq;
            }
#pragma unroll
            for (int ct = 2; ct < 4; ++ct) {   // k -> Ks[row][dim]
                uint2 wk = {cvtpk(acc[i][ct][0], acc[i][ct][1]),
                            cvtpk(acc[i][ct][2], acc[i][ct][3])};
                *(uint2*)&Ks[row * 40 + (ct - 2) * 16 + qd * 4] = wk;
            }
#pragma unroll
            for (int ct = 4; ct < 6; ++ct)     // v -> Vt[dim][row] (transposed)
#pragma unroll
                for (int r = 0; r < 4; ++r)
                    Vt[((ct - 4) * 16 + qd * 4 + r) * 328 + row] = f2bf(acc[i][ct][r]);
        }
    }
    float g = 1.f / (1.f + __expf(-gating[h]));
    float omg = 1.f - g;
    __syncthreads();

    // -------- attention phase (pair-packed loop) --------
    const ushort* ksp0 = &Ks[li * 40 + qd * 8];
    const ushort* vtp0 = &Vt[li * 328 + qd * 4];
    const ushort* vtp1 = &Vt[(16 + li) * 328 + qd * 4];
    const v4f z4 = {0.f, 0.f, 0.f, 0.f};

    for (int rg = wave; rg < 19; rg += 4) {
        int i0 = rg * 16;
        // Q rows >= 300 are exact zeros (zero-padded X) -> masked at store
        v8s bq = *(const v8s*)&Qs[(i0 + li) * 40 + qd * 8];
        const ushort* gp = gpos + ((size_t)h * 304 + (i0 + li)) * 304 + qd * 4;

        v4f Oe0 = z4, Oe1 = z4, Og0 = z4, Og1 = z4;
        float esum = 0.f;

        // prologue: load pair 0 (tiles 0,1) operands + compute its scores
        v8s ak0 = *(const v8s*)(ksp0);
        v8s ak1 = *(const v8s*)(ksp0 + 640);
        uint2 v0a = *(const uint2*)(vtp0);
        uint2 v0b = *(const uint2*)(vtp0 + 16);
        uint2 v1a = *(const uint2*)(vtp1);
        uint2 v1b = *(const uint2*)(vtp1 + 16);
        uint2 g0 = *(const uint2*)(gp);
        uint2 g1 = *(const uint2*)(gp + 16);
        v4f s0n = __builtin_amdgcn_mfma_f32_16x16x32_bf16(ak0, bq, z4, 0, 0, 0);
        v4f s1n = __builtin_amdgcn_mfma_f32_16x16x32_bf16(ak1, bq, z4, 0, 0, 0);

#pragma unroll 1
        for (int p = 0; p < 9; ++p) {          // pairs (nt=2p, 2p+1), nt<=17
            v4f s0 = s0n, s1 = s1n;
            v8s b0 = __builtin_bit_cast(v8s, (v4u){v0a.x, v0a.y, v0b.x, v0b.y});
            v8s b1 = __builtin_bit_cast(v8s, (v4u){v1a.x, v1a.y, v1b.x, v1b.y});
            v8s ag = __builtin_bit_cast(v8s, (v4u){g0.x, g0.y, g1.x, g1.y});
            int nt0 = 2 * p + 2;               // next pair (p=8 -> tail tile 18)
            int nt1 = (p < 8) ? nt0 + 1 : 18;
            ak0 = *(const v8s*)(ksp0 + nt0 * 640);
            ak1 = *(const v8s*)(ksp0 + nt1 * 640);
            v0a = *(const uint2*)(vtp0 + nt0 * 16);
            v0b = *(const uint2*)(vtp0 + nt1 * 16);
            v1a = *(const uint2*)(vtp1 + nt0 * 16);
            v1b = *(const uint2*)(vtp1 + nt1 * 16);
            g0 = *(const uint2*)(gp + nt0 * 16);
            g1 = *(const uint2*)(gp + nt1 * 16);
            s0n = __builtin_amdgcn_mfma_f32_16x16x32_bf16(ak0, bq, z4, 0, 0, 0);
            s1n = __builtin_amdgcn_mfma_f32_16x16x32_bf16(ak1, bq, z4, 0, 0, 0);

            float e0 = fexp2(s0[0]);           // log2(e) folded into q scale
            float e1 = fexp2(s0[1]);
            float e2 = fexp2(s0[2]);
            float e3 = fexp2(s0[3]);
            float f0 = fexp2(s1[0]);
            float f1 = fexp2(s1[1]);
            float f2 = fexp2(s1[2]);
            float f3 = fexp2(s1[3]);
            esum += ((e0 + e1) + (e2 + e3)) + ((f0 + f1) + (f2 + f3));
            v8s ae = __builtin_bit_cast(v8s, (v4u){cvtpk(e0, e1), cvtpk(e2, e3),
                                                   cvtpk(f0, f1), cvtpk(f2, f3)});
            __builtin_amdgcn_s_setprio(1);
            Oe0 = __builtin_amdgcn_mfma_f32_16x16x32_bf16(ae, b0, Oe0, 0, 0, 0);
            Oe1 = __builtin_amdgcn_mfma_f32_16x16x32_bf16(ae, b1, Oe1, 0, 0, 0);
            Og0 = __builtin_amdgcn_mfma_f32_16x16x32_bf16(ag, b0, Og0, 0, 0, 0);
            Og1 = __builtin_amdgcn_mfma_f32_16x16x32_bf16(ag, b1, Og1, 0, 0, 0);
            __builtin_amdgcn_s_setprio(0);
        }
        {   // tail tile nt=18 (j=288..303): scores in s0n, operands in regs
            float e0 = fexp2(s0n[0]);
            float e1 = fexp2(s0n[1]);
            float e2 = fexp2(s0n[2]);
            float e3 = fexp2(s0n[3]);
            if (qd == 3) { e0 = e1 = e2 = e3 = 0.f; }   // j >= 300
            esum += (e0 + e1) + (e2 + e3);
            v8s ae = __builtin_bit_cast(v8s, (v4u){cvtpk(e0, e1), cvtpk(e2, e3), 0u, 0u});
            v8s ag = __builtin_bit_cast(v8s, (v4u){g0.x, g0.y, 0u, 0u});
            v8s b0 = __builtin_bit_cast(v8s, (v4u){v0a.x, v0a.y, 0u, 0u});
            v8s b1 = __builtin_bit_cast(v8s, (v4u){v1a.x, v1a.y, 0u, 0u});
            Oe0 = __builtin_amdgcn_mfma_f32_16x16x32_bf16(ae, b0, Oe0, 0, 0, 0);
            Oe1 = __builtin_amdgcn_mfma_f32_16x16x32_bf16(ae, b1, Oe1, 0, 0, 0);
            Og0 = __builtin_amdgcn_mfma_f32_16x16x32_bf16(ag, b0, Og0, 0, 0, 0);
            Og1 = __builtin_amdgcn_mfma_f32_16x16x32_bf16(ag, b1, Og1, 0, 0, 0);
        }
        esum += __shfl_xor(esum, 16);
        esum += __shfl_xor(esum, 32);          // full row sum for query i0+li
        float ps = omg / esum;                 // (skip /attn.sum: it's 1 +- 1e-6)
        float psr[4];
#pragma unroll
        for (int r = 0; r < 4; ++r) psr[r] = __shfl(ps, qd * 4 + r);
#pragma unroll
        for (int r = 0; r < 4; ++r) {
            int row = i0 + qd * 4 + r;
            if (row < NSEQ) {
                int m = b * NSEQ + row;
                int rt = m >> 7, rr = m & 127;
                int c0 = (h & 1) * 4 + (li >> 3);
                int p2 = li & 7;
                size_t tb = ((size_t)(rt * 4 + (h >> 1)) * 128 + rr) * 64;
                ot[tb + ((c0 ^ (rr & 7)) * 8) + p2] = f2bf(fmaf(psr[r], Oe0[r], Og0[r]));
                ot[tb + (((c0 + 2) ^ (rr & 7)) * 8) + p2] = f2bf(fmaf(psr[r], Oe1[r], Og1[r]));
            }
        }
    }
}

// ---------------- K4: output projection, BM=64, DMA staging + bias ----------------
__global__ __launch_bounds__(256, 4) void gemm_proj_mfma(
    const ushort* __restrict__ A, const ushort* __restrict__ Bw,
    const float* __restrict__ bias, float* __restrict__ out)
{
    __shared__ ushort As[64 * 64];    // 8 KB
    __shared__ ushort Bs[128 * 64];   // 16 KB
    int tid = threadIdx.x;
    int wave = tid >> 6, lane = tid & 63, li = lane & 15, qd = lane >> 4;
    int rh = wave >> 1, ch = wave & 1;
    int by = blockIdx.y;
    const ushort* gA = A + ((size_t)(by >> 1) * 4 * 128 + (by & 1) * 64) * 64;
    const ushort* gB = Bw + (size_t)blockIdx.x * 4 * 8192;

    v4f acc[2][4];
#pragma unroll
    for (int i = 0; i < 2; ++i)
#pragma unroll
        for (int j = 0; j < 4; ++j) acc[i][j] = (v4f){0.f, 0.f, 0.f, 0.f};

    for (int kt = 0; kt < 4; ++kt) {
#pragma unroll
        for (int s = 0; s < 2; ++s) {
            int cch = s * 256 + tid;
            gl_lds16(gA + (size_t)kt * 128 * 64 + cch * 8, As + cch * 8);
        }
#pragma unroll
        for (int s = 0; s < 4; ++s) {
            int cch = s * 256 + tid;
            gl_lds16(gB + (size_t)kt * 8192 + cch * 8, Bs + cch * 8);
        }
        __syncthreads();
#pragma unroll
        for (int kc = 0; kc < 64; kc += 32) {
            int cb = (kc >> 3) + qd;
            int cs = cb ^ (li & 7);
            v8s a[2], b[4];
#pragma unroll
            for (int mt = 0; mt < 2; ++mt)
                a[mt] = *(const v8s*)&As[(rh * 32 + mt * 16 + li) * 64 + cs * 8];
#pragma unroll
            for (int nt = 0; nt < 4; ++nt)
                b[nt] = *(const v8s*)&Bs[(ch * 64 + nt * 16 + li) * 64 + cs * 8];
#pragma unroll
            for (int mt = 0; mt < 2; ++mt)
#pragma unroll
                for (int nt = 0; nt < 4; ++nt)
                    acc[mt][nt] = __builtin_amdgcn_mfma_f32_16x16x32_bf16(b[nt], a[mt], acc[mt][nt], 0, 0, 0);
        }
        __syncthreads();
    }

#pragma unroll
    for (int mt = 0; mt < 2; ++mt) {
        int row = by * 64 + rh * 32 + mt * 16 + li;
#pragma unroll
        for (int nt = 0; nt < 4; ++nt) {
            int col = blockIdx.x * 128 + ch * 64 + nt * 16 + qd * 4;
            float4 bv = *(const float4*)&bias[col];
            float4 st = {acc[mt][nt][0] + bv.x, acc[mt][nt][1] + bv.y,
                         acc[mt][nt][2] + bv.z, acc[mt][nt][3] + bv.w};
            *(float4*)&out[(size_t)row * 256 + col] = st;
        }
    }
}

extern "C" void kernel_launch(void* const* d_in, const int* in_sizes, int n_in,
                              void* d_out, int out_size, void* d_ws, size_t ws_size,
                              hipStream_t stream) {
    const float* x      = (const float*)d_in[0];
    const float* Wqk    = (const float*)d_in[1];
    const float* Wv     = (const float*)d_in[2];
    const float* Wpos   = (const float*)d_in[3];
    const float* bpos   = (const float*)d_in[4];
    const float* Wproj  = (const float*)d_in[5];
    const float* bproj  = (const float*)d_in[6];
    const float* gating = (const float*)d_in[7];
    float* out = (float*)d_out;

    ushort* gpos     = (ushort*)d_ws;             // 8*304*304 = 739,328
    ushort* Wf       = gpos + 739328;             // 8*4*96*64 = 196,608 (swizzled)
    ushort* wproj_t  = Wf + 196608;               // 65,536 (tiled+swizzled)
    ushort* o_t      = wproj_t + 65536;           // 4,915,200 (tiled+swizzled)
    ushort* x_bf     = o_t + 4915200;             // 64*304*256 = 4,980,736

    prep_kernel<<<3168, 256, 0, stream>>>(x, Wqk, Wv, Wproj, Wpos, bpos, gating,
                                          x_bf, Wf, wproj_t, gpos);
    fused_qkv_attn<<<512, 256, 0, stream>>>(x_bf, Wf, gpos, gating, o_t);
    gemm_proj_mfma<<<dim3(2, 300), 256, 0, stream>>>(o_t, wproj_t, bproj, out);
}